// Round 1
// baseline (710.979 us; speedup 1.0000x reference)
//
#include <hip/hip_runtime.h>
#include <cstdint>
#include <cmath>

#define H 32
#define HKV 8
#define DD 128
#define HID 4096
#define II 12288
#define SS 8192
#define EPSF 1e-6f
#define CS 256
#define NC (SS / CS) /* 32 */

__device__ __forceinline__ float wave_reduce_sum(float v) {
#pragma unroll
    for (int off = 32; off; off >>= 1) v += __shfl_down(v, off, 64);
    return v;
}

// ---------------- RMSNorm over n elements (single block, 256 threads) --------
__global__ __launch_bounds__(256) void rms_kernel(const float* __restrict__ x,
                                                  const float* __restrict__ w,
                                                  float* __restrict__ out, int n) {
    __shared__ float red[4];
    int t = threadIdx.x;
    int lane = t & 63, wave = t >> 6;
    const float4* x4 = (const float4*)x;
    int n4 = n >> 2;
    float ss = 0.f;
    for (int i = t; i < n4; i += 256) {
        float4 a = x4[i];
        ss += a.x * a.x + a.y * a.y + a.z * a.z + a.w * a.w;
    }
    ss = wave_reduce_sum(ss);
    if (lane == 0) red[wave] = ss;
    __syncthreads();
    float tot = red[0] + red[1] + red[2] + red[3];
    float r = rsqrtf(tot / (float)n + EPSF);
    const float4* w4 = (const float4*)w;
    float4* o4 = (float4*)out;
    for (int i = t; i < n4; i += 256) {
        float4 a = x4[i], b = w4[i];
        o4[i] = make_float4(a.x * r * b.x, a.y * r * b.y, a.z * r * b.z, a.w * r * b.w);
    }
}

// ---------------- Fused QKV GEMV: wave-per-row, rows 0..6143 -----------------
__global__ __launch_bounds__(256) void gemv_qkv(const float* __restrict__ Wq,
                                                const float* __restrict__ Wk,
                                                const float* __restrict__ Wv,
                                                const float* __restrict__ h,
                                                float* __restrict__ q,
                                                float* __restrict__ k,
                                                float* __restrict__ v) {
    int wave = threadIdx.x >> 6, lane = threadIdx.x & 63;
    int row = blockIdx.x * 4 + wave;
    const float* wrow;
    float* out;
    int r;
    if (row < 4096) { wrow = Wq + (size_t)row * HID; out = q; r = row; }
    else if (row < 5120) { wrow = Wk + (size_t)(row - 4096) * HID; out = k; r = row - 4096; }
    else { wrow = Wv + (size_t)(row - 5120) * HID; out = v; r = row - 5120; }
    const float4* w4 = (const float4*)wrow;
    const float4* h4 = (const float4*)h;
    float acc = 0.f;
#pragma unroll
    for (int ii = 0; ii < 16; ii++) {
        int i = lane + ii * 64;
        float4 a = w4[i], b = h4[i];
        acc += a.x * b.x + a.y * b.y + a.z * b.z + a.w * b.w;
    }
    acc = wave_reduce_sum(acc);
    if (lane == 0) out[r] = acc;
}

// ---------------- q/k RMSNorm + RoPE (40 blocks x 128 threads) ---------------
__global__ __launch_bounds__(128) void qk_norm_rope(float* __restrict__ q,
                                                    float* __restrict__ k,
                                                    const float* __restrict__ cv,
                                                    const float* __restrict__ sv,
                                                    const float* __restrict__ qw,
                                                    const float* __restrict__ kw) {
    int b = blockIdx.x, t = threadIdx.x;
    bool isq = (b < H);
    float* vec = isq ? (q + (size_t)b * DD) : (k + (size_t)(b - H) * DD);
    const float* nw = isq ? qw : kw;
    __shared__ float sh[DD];
    __shared__ float red[DD];
    float val = vec[t];
    red[t] = val * val;
    __syncthreads();
#pragma unroll
    for (int off = 64; off; off >>= 1) {
        if (t < off) red[t] += red[t + off];
        __syncthreads();
    }
    float r = rsqrtf(red[0] / (float)DD + EPSF);
    float nv = val * r * nw[t];
    sh[t] = nv;
    __syncthreads();
    float other = (t < 64) ? -sh[t + 64] : sh[t - 64];
    vec[t] = nv * cv[t] + other * sv[t];
}

// ---------------- KV cache copy with new-row insert --------------------------
// grid (8192, 2), 256 threads; each thread one float4. blockIdx.y: 0=k, 1=v
__global__ __launch_bounds__(256) void kv_copy(const float* __restrict__ kc,
                                               const float* __restrict__ vc,
                                               const float* __restrict__ kn,
                                               const float* __restrict__ vn,
                                               const float* __restrict__ position,
                                               float* __restrict__ ok,
                                               float* __restrict__ ov) {
    int pos = (int)position[0];
    size_t i = (size_t)blockIdx.x * 256 + threadIdx.x;  // float4 index in tensor
    const float4* src4 = (blockIdx.y == 0) ? (const float4*)kc : (const float4*)vc;
    const float4* new4 = (blockIdx.y == 0) ? (const float4*)kn : (const float4*)vn;
    float4* dst4 = (blockIdx.y == 0) ? (float4*)ok : (float4*)ov;
    int s = (int)((i >> 5) & (SS - 1));  // 32 float4 per row of 128 floats
    float4 val;
    if (s == pos) {
        int head = (int)(i >> 18);  // / (32*8192)
        int d4 = (int)(i & 31);
        val = new4[head * 32 + d4];
    } else {
        val = src4[i];
    }
    dst4[i] = val;
}

// ---------------- Attention: chunked flash-decode partials -------------------
// grid (H, NC), 256 threads
__global__ __launch_bounds__(256) void attn_partial(const float* __restrict__ q,
                                                    const float* __restrict__ ok,
                                                    const float* __restrict__ ov,
                                                    const float* __restrict__ position,
                                                    float* __restrict__ pm,
                                                    float* __restrict__ pl,
                                                    float* __restrict__ po) {
    int h = blockIdx.x, c = blockIdx.y, t = threadIdx.x;
    int kvh = h >> 2;
    int pos = (int)position[0];
    __shared__ float qs[DD];
    __shared__ float red[CS];
    __shared__ float pv[CS];
    if (t < DD) qs[t] = q[h * DD + t];
    __syncthreads();
    int s = c * CS + t;
    float score = -INFINITY;
    if (s <= pos) {
        const float4* kr = (const float4*)(ok + ((size_t)kvh * SS + s) * DD);
        const float4* q4 = (const float4*)qs;
        float acc = 0.f;
#pragma unroll
        for (int i = 0; i < DD / 4; i++) {
            float4 a = kr[i], b = q4[i];
            acc += a.x * b.x + a.y * b.y + a.z * b.z + a.w * b.w;
        }
        score = acc * 0.08838834764831845f;  // 1/sqrt(128)
    }
    red[t] = score;
    __syncthreads();
#pragma unroll
    for (int off = 128; off; off >>= 1) {
        if (t < off) red[t] = fmaxf(red[t], red[t + off]);
        __syncthreads();
    }
    float m = red[0];
    __syncthreads();  // all threads got m before red reuse
    float p = (score == -INFINITY) ? 0.f : expf(score - m);
    pv[t] = p;
    red[t] = p;
    __syncthreads();
#pragma unroll
    for (int off = 128; off; off >>= 1) {
        if (t < off) red[t] += red[t + off];
        __syncthreads();
    }
    float l = red[0];
    int jend = pos + 1 - c * CS;
    if (jend > CS) jend = CS;
    if (t < DD) {
        float acc = 0.f;
        for (int j = 0; j < jend; j++) {
            acc += pv[j] * ov[((size_t)kvh * SS + (size_t)(c * CS + j)) * DD + t];
        }
        po[((size_t)h * NC + c) * DD + t] = acc;
    }
    if (t == 0) {
        pm[h * NC + c] = m;
        pl[h * NC + c] = l;
    }
}

// ---------------- Attention combine (H blocks x 128 threads) -----------------
__global__ __launch_bounds__(128) void attn_combine(const float* __restrict__ pm,
                                                    const float* __restrict__ pl,
                                                    const float* __restrict__ po,
                                                    float* __restrict__ ao) {
    int h = blockIdx.x, d = threadIdx.x;
    float M = -INFINITY;
    for (int c = 0; c < NC; c++) M = fmaxf(M, pm[h * NC + c]);
    float L = 0.f, acc = 0.f;
    for (int c = 0; c < NC; c++) {
        float mm = pm[h * NC + c];
        if (mm == -INFINITY) continue;
        float wgt = expf(mm - M);
        L += wgt * pl[h * NC + c];
        acc += wgt * po[((size_t)h * NC + c) * DD + d];
    }
    ao[h * DD + d] = acc / L;
}

// ---------------- Wo GEMV + residual (wave-per-row, 4096 rows) ---------------
__global__ __launch_bounds__(256) void gemv_wo(const float* __restrict__ W,
                                               const float* __restrict__ xin,
                                               const float* __restrict__ resid,
                                               float* __restrict__ out) {
    int wave = threadIdx.x >> 6, lane = threadIdx.x & 63;
    int row = blockIdx.x * 4 + wave;
    const float4* w4 = (const float4*)(W + (size_t)row * HID);
    const float4* x4 = (const float4*)xin;
    float acc = 0.f;
#pragma unroll
    for (int ii = 0; ii < 16; ii++) {
        int i = lane + ii * 64;
        float4 a = w4[i], b = x4[i];
        acc += a.x * b.x + a.y * b.y + a.z * b.z + a.w * b.w;
    }
    acc = wave_reduce_sum(acc);
    if (lane == 0) out[row] = resid[row] + acc;
}

// ---------------- Gate/Up fused GEMV + SiLU (12288 rows) ---------------------
__global__ __launch_bounds__(256) void gemv_gateup(const float* __restrict__ Wg,
                                                   const float* __restrict__ Wu,
                                                   const float* __restrict__ h2,
                                                   float* __restrict__ m) {
    int wave = threadIdx.x >> 6, lane = threadIdx.x & 63;
    int row = blockIdx.x * 4 + wave;
    const float4* g4 = (const float4*)(Wg + (size_t)row * HID);
    const float4* u4 = (const float4*)(Wu + (size_t)row * HID);
    const float4* x4 = (const float4*)h2;
    float accg = 0.f, accu = 0.f;
#pragma unroll
    for (int ii = 0; ii < 16; ii++) {
        int i = lane + ii * 64;
        float4 b = x4[i];
        float4 a = g4[i];
        accg += a.x * b.x + a.y * b.y + a.z * b.z + a.w * b.w;
        float4 cvu = u4[i];
        accu += cvu.x * b.x + cvu.y * b.y + cvu.z * b.z + cvu.w * b.w;
    }
    accg = wave_reduce_sum(accg);
    accu = wave_reduce_sum(accu);
    if (lane == 0) {
        float g = accg;
        m[row] = (g / (1.f + expf(-g))) * accu;  // silu(g) * u
    }
}

// ---------------- Down GEMV + residual (4096 rows, K=12288) ------------------
__global__ __launch_bounds__(256) void gemv_down(const float* __restrict__ Wd,
                                                 const float* __restrict__ mi,
                                                 const float* __restrict__ h1,
                                                 float* __restrict__ out) {
    int wave = threadIdx.x >> 6, lane = threadIdx.x & 63;
    int row = blockIdx.x * 4 + wave;
    const float4* w4 = (const float4*)(Wd + (size_t)row * II);
    const float4* x4 = (const float4*)mi;
    float acc = 0.f;
#pragma unroll
    for (int ii = 0; ii < 48; ii++) {
        int i = lane + ii * 64;
        float4 a = w4[i], b = x4[i];
        acc += a.x * b.x + a.y * b.y + a.z * b.z + a.w * b.w;
    }
    acc = wave_reduce_sum(acc);
    if (lane == 0) out[row] = h1[row] + acc;
}

extern "C" void kernel_launch(void* const* d_in, const int* in_sizes, int n_in,
                              void* d_out, int out_size, void* d_ws, size_t ws_size,
                              hipStream_t stream) {
    const float* x        = (const float*)d_in[0];   // hidden_conv (4096)
    const float* position = (const float*)d_in[1];
    const float* cosv     = (const float*)d_in[2];
    const float* sinv     = (const float*)d_in[3];
    const float* k_cache  = (const float*)d_in[4];
    const float* v_cache  = (const float*)d_in[5];
    const float* Wq       = (const float*)d_in[6];
    const float* Wk       = (const float*)d_in[7];
    const float* Wv       = (const float*)d_in[8];
    const float* Wo       = (const float*)d_in[9];
    const float* Wg       = (const float*)d_in[10];
    const float* Wu       = (const float*)d_in[11];
    const float* Wd       = (const float*)d_in[12];
    const float* q_norm_w = (const float*)d_in[13];
    const float* k_norm_w = (const float*)d_in[14];
    const float* ln1_w    = (const float*)d_in[15];
    const float* ln2_w    = (const float*)d_in[16];

    float* out_hid = (float*)d_out;
    float* out_k   = out_hid + HID;
    float* out_v   = out_k + (size_t)HKV * SS * DD;

    float* ws = (float*)d_ws;
    float* h        = ws;                  // 4096
    float* q        = h + HID;             // 4096
    float* k        = q + H * DD;          // 1024
    float* v        = k + HKV * DD;        // 1024
    float* attn_out = v + HKV * DD;        // 4096
    float* h1       = attn_out + H * DD;   // 4096
    float* h2       = h1 + HID;            // 4096
    float* mi       = h2 + HID;            // 12288
    float* part_m   = mi + II;             // H*NC = 1024
    float* part_l   = part_m + H * NC;     // 1024
    float* part_o   = part_l + H * NC;     // H*NC*128 = 131072

    rms_kernel<<<1, 256, 0, stream>>>(x, ln1_w, h, HID);
    gemv_qkv<<<1536, 256, 0, stream>>>(Wq, Wk, Wv, h, q, k, v);
    qk_norm_rope<<<H + HKV, 128, 0, stream>>>(q, k, cosv, sinv, q_norm_w, k_norm_w);
    kv_copy<<<dim3(8192, 2), 256, 0, stream>>>(k_cache, v_cache, k, v, position, out_k, out_v);
    attn_partial<<<dim3(H, NC), 256, 0, stream>>>(q, out_k, out_v, position, part_m, part_l, part_o);
    attn_combine<<<H, 128, 0, stream>>>(part_m, part_l, part_o, attn_out);
    gemv_wo<<<1024, 256, 0, stream>>>(Wo, attn_out, x, h1);
    rms_kernel<<<1, 256, 0, stream>>>(h1, ln2_w, h2, HID);
    gemv_gateup<<<3072, 256, 0, stream>>>(Wg, Wu, h2, mi);
    gemv_down<<<1024, 256, 0, stream>>>(Wd, mi, h1, out_hid);
}

// Round 2
// 695.831 us; speedup vs baseline: 1.0218x; 1.0218x over previous
//
#include <hip/hip_runtime.h>
#include <cstdint>
#include <cmath>

#define H 32
#define HKV 8
#define DD 128
#define HID 4096
#define II 12288
#define SS 8192
#define EPSF 1e-6f
#define CS 256
#define NC (SS / CS) /* 32 */

typedef float f4 __attribute__((ext_vector_type(4)));

__device__ __forceinline__ float wave_reduce_sum(float v) {
#pragma unroll
    for (int off = 32; off; off >>= 1) v += __shfl_down(v, off, 64);
    return v;
}

__device__ __forceinline__ f4 ntload(const f4* p) {
    return __builtin_nontemporal_load(p);
}

// ---------------- KV bulk copy (pure stream, independent of everything) ------
// grid (2048, 2) x 256: each thread 4 float4s. blockIdx.y: 0=k, 1=v
__global__ __launch_bounds__(256) void kv_bulk(const float* __restrict__ kc,
                                               const float* __restrict__ vc,
                                               float* __restrict__ ok,
                                               float* __restrict__ ov) {
    const f4* src = (blockIdx.y == 0) ? (const f4*)kc : (const f4*)vc;
    f4* dst = (blockIdx.y == 0) ? (f4*)ok : (f4*)ov;
    size_t base = (size_t)blockIdx.x * 1024 + threadIdx.x;
#pragma unroll
    for (int j = 0; j < 4; j++) {
        size_t i = base + (size_t)j * 256;
        __builtin_nontemporal_store(ntload(src + i), dst + i);
    }
}

// ---------------- Fused RMSNorm + QKV GEMV -----------------------------------
// grid 1536 x 256. Each block: recompute rms scale of x, then 4 waves x 1 row.
__global__ __launch_bounds__(256) void gemv_qkv(const float* __restrict__ Wq,
                                                const float* __restrict__ Wk,
                                                const float* __restrict__ Wv,
                                                const float* __restrict__ x,
                                                const float* __restrict__ ln1,
                                                float* __restrict__ q,
                                                float* __restrict__ k,
                                                float* __restrict__ v) {
    __shared__ float red[4];
    int t = threadIdx.x;
    int wave = t >> 6, lane = t & 63;
    const f4* x4 = (const f4*)x;
    const f4* l4 = (const f4*)ln1;
    // block-redundant rms scale (x is L1/L2-resident: 16KB)
    float ss = 0.f;
#pragma unroll
    for (int i = 0; i < 4; i++) {
        f4 a = x4[t + i * 256];
        ss += a.x * a.x + a.y * a.y + a.z * a.z + a.w * a.w;
    }
    ss = wave_reduce_sum(ss);
    if (lane == 0) red[wave] = ss;
    __syncthreads();
    float r = rsqrtf((red[0] + red[1] + red[2] + red[3]) * (1.f / (float)HID) + EPSF);

    int row = blockIdx.x * 4 + wave;
    const float* wrow;
    float* out;
    int ro;
    if (row < 4096)      { wrow = Wq + (size_t)row * HID;          out = q; ro = row; }
    else if (row < 5120) { wrow = Wk + (size_t)(row - 4096) * HID; out = k; ro = row - 4096; }
    else                 { wrow = Wv + (size_t)(row - 5120) * HID; out = v; ro = row - 5120; }
    const f4* w4 = (const f4*)wrow;
    float acc = 0.f;
#pragma unroll
    for (int ii = 0; ii < 16; ii++) {
        int i = lane + ii * 64;
        f4 a = ntload(w4 + i);
        f4 b = x4[i];
        f4 c = l4[i];
        acc += a.x * b.x * c.x + a.y * b.y * c.y + a.z * b.z * c.z + a.w * b.w * c.w;
    }
    acc = wave_reduce_sum(acc);
    if (lane == 0) out[ro] = acc * r;
}

// ---------------- q/k RMSNorm + RoPE + KV-row insert -------------------------
// grid 48 x 128. b<32: q in place. 32..39: k -> out_k[pos]. 40..47: v -> out_v[pos].
__global__ __launch_bounds__(128) void rope_insert(float* __restrict__ q,
                                                   const float* __restrict__ k,
                                                   const float* __restrict__ v,
                                                   const float* __restrict__ cv,
                                                   const float* __restrict__ sv,
                                                   const float* __restrict__ qw,
                                                   const float* __restrict__ kw,
                                                   const float* __restrict__ position,
                                                   float* __restrict__ ok,
                                                   float* __restrict__ ov) {
    int b = blockIdx.x, t = threadIdx.x;
    int pos = (int)position[0];
    if (b >= 40) {  // v rows: plain insert, no norm/rope
        int hv = b - 40;
        ov[((size_t)hv * SS + pos) * DD + t] = v[hv * DD + t];
        return;
    }
    bool isq = (b < H);
    const float* vec = isq ? (q + (size_t)b * DD) : (k + (size_t)(b - H) * DD);
    const float* nw = isq ? qw : kw;
    __shared__ float sh[DD];
    __shared__ float red[DD];
    float val = vec[t];
    red[t] = val * val;
    __syncthreads();
#pragma unroll
    for (int off = 64; off; off >>= 1) {
        if (t < off) red[t] += red[t + off];
        __syncthreads();
    }
    float r = rsqrtf(red[0] * (1.f / (float)DD) + EPSF);
    float nv = val * r * nw[t];
    sh[t] = nv;
    __syncthreads();
    float other = (t < 64) ? -sh[t + 64] : sh[t - 64];
    float res = nv * cv[t] + other * sv[t];
    if (isq) {
        q[(size_t)b * DD + t] = res;
    } else {
        int hk = b - H;
        ok[((size_t)hk * SS + pos) * DD + t] = res;
    }
}

// ---------------- Attention: chunked flash-decode partials -------------------
// grid (H, NC), 256 threads
__global__ __launch_bounds__(256) void attn_partial(const float* __restrict__ q,
                                                    const float* __restrict__ ok,
                                                    const float* __restrict__ ov,
                                                    const float* __restrict__ position,
                                                    float* __restrict__ pm,
                                                    float* __restrict__ pl,
                                                    float* __restrict__ po) {
    int h = blockIdx.x, c = blockIdx.y, t = threadIdx.x;
    int kvh = h >> 2;
    int pos = (int)position[0];
    if (c * CS > pos) {  // fully-masked chunk
        if (t == 0) { pm[h * NC + c] = -INFINITY; pl[h * NC + c] = 0.f; }
        return;
    }
    __shared__ float qs[DD];
    __shared__ float red[CS];
    __shared__ float pv[CS];
    if (t < DD) qs[t] = q[h * DD + t];
    __syncthreads();
    int s = c * CS + t;
    float score = -INFINITY;
    if (s <= pos) {
        const f4* kr = (const f4*)(ok + ((size_t)kvh * SS + s) * DD);
        const f4* q4 = (const f4*)qs;
        float acc = 0.f;
#pragma unroll
        for (int i = 0; i < DD / 4; i++) {
            f4 a = kr[i], b = q4[i];
            acc += a.x * b.x + a.y * b.y + a.z * b.z + a.w * b.w;
        }
        score = acc * 0.08838834764831845f;  // 1/sqrt(128)
    }
    red[t] = score;
    __syncthreads();
#pragma unroll
    for (int off = 128; off; off >>= 1) {
        if (t < off) red[t] = fmaxf(red[t], red[t + off]);
        __syncthreads();
    }
    float m = red[0];
    __syncthreads();
    float p = (score == -INFINITY) ? 0.f : expf(score - m);
    pv[t] = p;
    red[t] = p;
    __syncthreads();
#pragma unroll
    for (int off = 128; off; off >>= 1) {
        if (t < off) red[t] += red[t + off];
        __syncthreads();
    }
    float l = red[0];
    int jend = pos + 1 - c * CS;
    if (jend > CS) jend = CS;
    if (t < DD) {
        float acc = 0.f;
        for (int j = 0; j < jend; j++) {
            acc += pv[j] * ov[((size_t)kvh * SS + (size_t)(c * CS + j)) * DD + t];
        }
        po[((size_t)h * NC + c) * DD + t] = acc;
    }
    if (t == 0) {
        pm[h * NC + c] = m;
        pl[h * NC + c] = l;
    }
}

// ---------------- Attention combine (H blocks x 128 threads) -----------------
__global__ __launch_bounds__(128) void attn_combine(const float* __restrict__ pm,
                                                    const float* __restrict__ pl,
                                                    const float* __restrict__ po,
                                                    float* __restrict__ ao) {
    int h = blockIdx.x, d = threadIdx.x;
    float M = -INFINITY;
    for (int c = 0; c < NC; c++) M = fmaxf(M, pm[h * NC + c]);
    float L = 0.f, acc = 0.f;
    for (int c = 0; c < NC; c++) {
        float mm = pm[h * NC + c];
        if (mm == -INFINITY) continue;
        float wgt = expf(mm - M);
        L += wgt * pl[h * NC + c];
        acc += wgt * po[((size_t)h * NC + c) * DD + d];
    }
    ao[h * DD + d] = acc / L;
}

// ---------------- Wo GEMV + residual (wave-per-row, 4096 rows) ---------------
__global__ __launch_bounds__(256) void gemv_wo(const float* __restrict__ W,
                                               const float* __restrict__ xin,
                                               const float* __restrict__ resid,
                                               float* __restrict__ out) {
    int wave = threadIdx.x >> 6, lane = threadIdx.x & 63;
    int row = blockIdx.x * 4 + wave;
    const f4* w4 = (const f4*)(W + (size_t)row * HID);
    const f4* x4 = (const f4*)xin;
    float acc = 0.f;
#pragma unroll
    for (int ii = 0; ii < 16; ii++) {
        int i = lane + ii * 64;
        f4 a = ntload(w4 + i);
        f4 b = x4[i];
        acc += a.x * b.x + a.y * b.y + a.z * b.z + a.w * b.w;
    }
    acc = wave_reduce_sum(acc);
    if (lane == 0) out[row] = resid[row] + acc;
}

// ---------------- Fused RMSNorm + Gate/Up GEMV + SiLU (12288 rows) -----------
__global__ __launch_bounds__(256) void gemv_gateup(const float* __restrict__ Wg,
                                                   const float* __restrict__ Wu,
                                                   const float* __restrict__ h1,
                                                   const float* __restrict__ ln2,
                                                   float* __restrict__ m) {
    __shared__ float red[4];
    int t = threadIdx.x;
    int wave = t >> 6, lane = t & 63;
    const f4* x4 = (const f4*)h1;
    const f4* l4 = (const f4*)ln2;
    float ss = 0.f;
#pragma unroll
    for (int i = 0; i < 4; i++) {
        f4 a = x4[t + i * 256];
        ss += a.x * a.x + a.y * a.y + a.z * a.z + a.w * a.w;
    }
    ss = wave_reduce_sum(ss);
    if (lane == 0) red[wave] = ss;
    __syncthreads();
    float r = rsqrtf((red[0] + red[1] + red[2] + red[3]) * (1.f / (float)HID) + EPSF);

    int row = blockIdx.x * 4 + wave;
    const f4* g4 = (const f4*)(Wg + (size_t)row * HID);
    const f4* u4 = (const f4*)(Wu + (size_t)row * HID);
    float accg = 0.f, accu = 0.f;
#pragma unroll
    for (int ii = 0; ii < 16; ii++) {
        int i = lane + ii * 64;
        f4 b = x4[i];
        f4 c = l4[i];
        f4 hb; hb.x = b.x * c.x; hb.y = b.y * c.y; hb.z = b.z * c.z; hb.w = b.w * c.w;
        f4 a = ntload(g4 + i);
        accg += a.x * hb.x + a.y * hb.y + a.z * hb.z + a.w * hb.w;
        f4 u = ntload(u4 + i);
        accu += u.x * hb.x + u.y * hb.y + u.z * hb.z + u.w * hb.w;
    }
    accg = wave_reduce_sum(accg);
    accu = wave_reduce_sum(accu);
    if (lane == 0) {
        float g = accg * r, uu = accu * r;
        m[row] = (g / (1.f + expf(-g))) * uu;  // silu(g) * u
    }
}

// ---------------- Down GEMV + residual (4096 rows, K=12288) ------------------
__global__ __launch_bounds__(256) void gemv_down(const float* __restrict__ Wd,
                                                 const float* __restrict__ mi,
                                                 const float* __restrict__ h1,
                                                 float* __restrict__ out) {
    int wave = threadIdx.x >> 6, lane = threadIdx.x & 63;
    int row = blockIdx.x * 4 + wave;
    const f4* w4 = (const f4*)(Wd + (size_t)row * II);
    const f4* x4 = (const f4*)mi;
    float acc = 0.f;
    for (int o = 0; o < 3; o++) {  // bounded unroll: <=16 loads in flight
#pragma unroll
        for (int ii = 0; ii < 16; ii++) {
            int i = lane + (o * 16 + ii) * 64;
            f4 a = ntload(w4 + i);
            f4 b = x4[i];
            acc += a.x * b.x + a.y * b.y + a.z * b.z + a.w * b.w;
        }
    }
    acc = wave_reduce_sum(acc);
    if (lane == 0) out[row] = h1[row] + acc;
}

extern "C" void kernel_launch(void* const* d_in, const int* in_sizes, int n_in,
                              void* d_out, int out_size, void* d_ws, size_t ws_size,
                              hipStream_t stream) {
    const float* x        = (const float*)d_in[0];   // hidden_conv (4096)
    const float* position = (const float*)d_in[1];
    const float* cosv     = (const float*)d_in[2];
    const float* sinv     = (const float*)d_in[3];
    const float* k_cache  = (const float*)d_in[4];
    const float* v_cache  = (const float*)d_in[5];
    const float* Wq       = (const float*)d_in[6];
    const float* Wk       = (const float*)d_in[7];
    const float* Wv       = (const float*)d_in[8];
    const float* Wo       = (const float*)d_in[9];
    const float* Wg       = (const float*)d_in[10];
    const float* Wu       = (const float*)d_in[11];
    const float* Wd       = (const float*)d_in[12];
    const float* q_norm_w = (const float*)d_in[13];
    const float* k_norm_w = (const float*)d_in[14];
    const float* ln1_w    = (const float*)d_in[15];
    const float* ln2_w    = (const float*)d_in[16];

    float* out_hid = (float*)d_out;
    float* out_k   = out_hid + HID;
    float* out_v   = out_k + (size_t)HKV * SS * DD;

    float* ws = (float*)d_ws;
    float* q        = ws;                  // 4096
    float* k        = q + H * DD;          // 1024
    float* v        = k + HKV * DD;        // 1024
    float* attn_out = v + HKV * DD;        // 4096
    float* h1       = attn_out + H * DD;   // 4096
    float* mi       = h1 + HID;            // 12288
    float* part_m   = mi + II;             // 1024
    float* part_l   = part_m + H * NC;     // 1024
    float* part_o   = part_l + H * NC;     // 131072

    kv_bulk<<<dim3(2048, 2), 256, 0, stream>>>(k_cache, v_cache, out_k, out_v);
    gemv_qkv<<<1536, 256, 0, stream>>>(Wq, Wk, Wv, x, ln1_w, q, k, v);
    rope_insert<<<48, 128, 0, stream>>>(q, k, v, cosv, sinv, q_norm_w, k_norm_w,
                                        position, out_k, out_v);
    attn_partial<<<dim3(H, NC), 256, 0, stream>>>(q, out_k, out_v, position,
                                                  part_m, part_l, part_o);
    attn_combine<<<H, 128, 0, stream>>>(part_m, part_l, part_o, attn_out);
    gemv_wo<<<1024, 256, 0, stream>>>(Wo, attn_out, x, h1);
    gemv_gateup<<<3072, 256, 0, stream>>>(Wg, Wu, h1, ln2_w, mi);
    gemv_down<<<1024, 256, 0, stream>>>(Wd, mi, h1, out_hid);
}